// Round 11
// baseline (421.621 us; speedup 1.0000x reference)
//
#include <hip/hip_runtime.h>
#include <hip/hip_cooperative_groups.h>
#include <math.h>

#define L_SEQ 8192
#define B_SZ  2
#define CH    256
#define NLEV  4

namespace cg = cooperative_groups;

typedef __attribute__((ext_vector_type(8))) short bf16x8;
typedef __attribute__((ext_vector_type(4))) float f32x4;

static __device__ __forceinline__ float sigmoidf_(float x) {
    return 1.0f / (1.0f + expf(-x));
}

// bf16 (stored as ushort) <-> fp32 helpers. bf2f is exact; f2b is RNE.
static __device__ __forceinline__ float bf2f_(unsigned short u) {
    union { unsigned int ui; float f; } x;
    x.ui = ((unsigned int)u) << 16;
    return x.f;
}
static __device__ __forceinline__ unsigned short f2b_(float f) {
    union { float f; unsigned int u; } x;
    x.f = f;
    unsigned int lsb = (x.u >> 16) & 1u;
    unsigned int r = x.u + 0x7fffu + lsb;
    return (unsigned short)(r >> 16);
}
static __device__ __forceinline__ float4 ldb4_(const unsigned short* p) {
    ushort4 u = *(const ushort4*)p;
    return make_float4(bf2f_(u.x), bf2f_(u.y), bf2f_(u.z), bf2f_(u.w));
}

// ---------------------------------------------------------------------------
// Fused fp32->bf16 prep + weight fold, one launch:
//   blocks [0, 17409):   guard row + x16 + qkv_w rows 0..511 + stem_w
//   blocks [17409, 17665): W'[c][j] = sum_k out_w[c][k]*qkv_w[512+k][j]
//     -> qw16 rows 512..767 (bf16).  Vp = v @ out_w^T, so attention's PV
//     output IS the level output: (P@V_win + v)@ow^T == P@Vp_win + Vp.
// ---------------------------------------------------------------------------
#define NPREP_BLOCKS 17409
__global__ __launch_bounds__(256) void prep_kernel(
    const float* __restrict__ x, const float* __restrict__ qkv_w,
    const float* __restrict__ out_w, const float* __restrict__ stem_w,
    unsigned short* __restrict__ x16g, unsigned short* __restrict__ qw16,
    unsigned short* __restrict__ sw16)
{
    __shared__ float owr[256];
    if (blockIdx.x >= NPREP_BLOCKS) {
        const int c = blockIdx.x - NPREP_BLOCKS, j = threadIdx.x;
        owr[j] = out_w[(size_t)c * 256 + j];
        __syncthreads();
        float acc = 0.0f;
        #pragma unroll 8
        for (int k = 0; k < 256; ++k)
            acc += owr[k] * qkv_w[(size_t)(512 + k) * 256 + j];
        qw16[(size_t)(512 + c) * 256 + j] = f2b_(acc);
        return;
    }
    int i = blockIdx.x * 256 + threadIdx.x;
    if (i < 256) { x16g[i] = 0; return; }           // guard row of zeros
    i -= 256;
    if (i < 4194304) { x16g[256 + i] = f2b_(x[i]); return; }
    i -= 4194304;
    if (i < 131072) { qw16[i] = f2b_(qkv_w[i]); return; }  // q,k rows only
    i -= 131072;
    {   // stem W: (256,512); k<256 -> tap0, else tap1
        int k = i & 511, nn = i >> 9;
        float v = (k < 256) ? stem_w[(size_t)nn * 512 + k * 2]
                            : stem_w[(size_t)nn * 512 + (k - 256) * 2 + 1];
        sw16[i] = f2b_(v);
    }
}

// ---------------------------------------------------------------------------
// Level body (round-10 code verbatim, logical-bid parameterized):
// 64-row tile, 16 waves.  qkv projection + width head + QK^T (K-split x2)
// + softmax (+Vp residual via P-center +1) + Vp projection + PV + downsample.
// STEM=1: also computes h = conv(x)+bias in-block.
// LDS plan within smem[127232]: hs@0, xs/qs/vt@40960, ks@73728, pb@114688,
// sp1@118784, ws1@126976.  Bitwise-identical chains to round 10.
// ---------------------------------------------------------------------------
template<int STEM>
static __device__ void do_level(
    char* smem, int lbid, int nwg,
    const unsigned short* __restrict__ h16in, const unsigned short* __restrict__ x16g,
    const unsigned short* __restrict__ sw, const float* __restrict__ sbias,
    const unsigned short* __restrict__ qw,
    const float* __restrict__ ww, const float* __restrict__ wbp,
    unsigned short* __restrict__ l16o, unsigned short* __restrict__ dsB, int l)
{
    unsigned short* hs = (unsigned short*)smem;              // 40960 B
    unsigned short* xs = (unsigned short*)(smem + 40960);    // 41472 B (alias)
    unsigned short* qs = (unsigned short*)(smem + 40960);    // 32768 B
    unsigned short* ks = (unsigned short*)(smem + 73728);    // 40960 B
    unsigned short* vt = (unsigned short*)(smem + 40960);    // 45056 B (alias)
    unsigned short* pb = (unsigned short*)(smem + 114688);   //  4096 B
    float* sp1 = (float*)(smem + 118784);                    //  8192 B
    float* ws1 = (float*)(smem + 126976);                    //   256 B

    const int tid  = threadIdx.x;
    const int wave = tid >> 6;        // 0..15
    const int lane = tid & 63;
    const int rt8  = wave & 3;        // QK/softmax row tile (waves 0..7)
    const int half = (wave >> 2) & 1; // QK channel half (waves 0..7)
    const int q    = lane >> 4;
    const int n    = lane & 15;
    const int ct   = wave;            // projection col tile 0..15

    // XCD-aware swizzle (nwg is always a multiple of 8)
    int bid = lbid;
    const int cpx = nwg >> 3;
    bid = (bid & 7) * cpx + (bid >> 3);

    const int bps = l >> 6;
    const int b  = bid / bps;
    const int t0 = (bid % bps) << 6;
    const size_t seqbase = (size_t)b * l;

    if constexpr (STEM) {
        // ---- stage x halo: 81 rows (gx = t0-9 .. t0+71), pre-swizzled src --
        #pragma unroll
        for (int i = 0; i < 3; ++i) {
            const int task = i * 1024 + tid;
            if (task < 2592) {
                const int r = task >> 5, ch = task & 31;
                const int gx = t0 - 9 + r;
                const unsigned short* src = (gx >= 0 && gx < l)
                    ? x16g + ((size_t)(seqbase + gx) + 1) * 256 + ((ch ^ (r & 7)) << 3)
                    : x16g;                       // guard zeros
                __builtin_amdgcn_global_load_lds(
                    (const __attribute__((address_space(1))) void*)src,
                    (__attribute__((address_space(3))) void*)
                        (xs + (size_t)(i * 1024 + (tid & ~63)) * 8),
                    16, 0, 0);
            }
        }
        __syncthreads();

        // ---- in-block stem GEMM: h rows 0..79 (halo); wave owns ct ----
        f32x4 accA[5] = {};
        #pragma unroll
        for (int pass = 0; pass < 2; ++pass) {
            bf16x8 wA[8];
            const unsigned short* wa_ = sw + (size_t)(ct * 16 + n) * 512 + pass * 256 + q * 8;
            #pragma unroll
            for (int j = 0; j < 8; ++j) wA[j] = *(const bf16x8*)(wa_ + j * 32);
            #pragma unroll
            for (int rtile = 0; rtile < 5; ++rtile) {
                const int xr = rtile * 16 + n + pass;
                const int xswz = (xr & 7) << 4;
                bf16x8 af[8];
                #pragma unroll
                for (int j = 0; j < 8; ++j)
                    af[j] = *(const bf16x8*)((const char*)xs +
                             ((xr * 512 + (j * 32 + q * 8) * 2) ^ xswz));
                #pragma unroll
                for (int j = 0; j < 8; ++j)
                    accA[rtile] = __builtin_amdgcn_mfma_f32_16x16x32_bf16(
                        af[j], wA[j], accA[rtile], 0, 0, 0);
            }
        }
        const float bA = sbias[ct * 16 + n];
        #pragma unroll
        for (int rtile = 0; rtile < 5; ++rtile)
            #pragma unroll
            for (int idx = 0; idx < 4; ++idx) {
                const int row = rtile * 16 + q * 4 + idx;     // 0..79
                const int growh = t0 - 8 + row;
                const int rswz = (row & 7) << 4;
                const bool ok = (growh >= 0 && growh < l);
                *(unsigned short*)((char*)hs +
                    ((row * 512 + (ct * 16 + n) * 2) ^ rswz)) =
                        ok ? f2b_(accA[rtile][idx] + bA) : (unsigned short)0;
            }
        __syncthreads();   // hs computed (xs now dead -> qs/ks may overwrite)
    } else {
        // ---- stage H halo (80 rows x 256 ch); source pre-swizzled ----
        #pragma unroll
        for (int i = 0; i < 3; ++i) {
            const int task = i * 1024 + tid;
            if (task < 2560) {
                const int r = task >> 5, ch = task & 31;
                const int grow = t0 - 8 + r;
                const unsigned short* src = (grow >= 0 && grow < l)
                    ? h16in + (seqbase + grow) * 256 + ((ch ^ (r & 7)) << 3)
                    : x16g;                       // 512 B of zeros (guard)
                __builtin_amdgcn_global_load_lds(
                    (const __attribute__((address_space(1))) void*)src,
                    (__attribute__((address_space(3))) void*)
                        (hs + (size_t)(i * 1024 + (tid & ~63)) * 8),
                    16, 0, 0);
            }
        }
        __syncthreads();
    }

    // ======== phase A: project q,k — wave owns ONE col-tile ct ========
    {   // ---- q (weight rows 0..255) -> qs rows 0..63 ----
        bf16x8 bwa[8];
        const unsigned short* wa_ = qw + (size_t)(ct * 16 + n) * 256 + q * 8;
        #pragma unroll
        for (int j = 0; j < 8; ++j) bwa[j] = *(const bf16x8*)(wa_ + j * 32);
        #pragma unroll
        for (int rtq = 0; rtq < 4; ++rtq) {
            const int hr = 8 + rtq * 16 + n;
            const int hswz = (hr & 7) << 4;
            bf16x8 af[8];
            #pragma unroll
            for (int j = 0; j < 8; ++j)
                af[j] = *(const bf16x8*)((const char*)hs +
                         ((hr * 512 + (j * 32 + q * 8) * 2) ^ hswz));
            f32x4 aA = {};
            #pragma unroll
            for (int j = 0; j < 8; ++j)
                aA = __builtin_amdgcn_mfma_f32_16x16x32_bf16(af[j], bwa[j], aA, 0, 0, 0);
            #pragma unroll
            for (int idx = 0; idx < 4; ++idx) {
                const int row = rtq * 16 + q * 4 + idx;
                const int rswz = (row & 7) << 4;
                *(unsigned short*)((char*)qs +
                    ((row * 512 + (ct * 16 + n) * 2) ^ rswz)) = f2b_(aA[idx]);
            }
        }
    }
    {   // ---- k (weight rows 256..511) -> ks halo rows 0..79 ----
        bf16x8 bwa[8];
        const unsigned short* wa_ = qw + (size_t)(256 + ct * 16 + n) * 256 + q * 8;
        #pragma unroll
        for (int j = 0; j < 8; ++j) bwa[j] = *(const bf16x8*)(wa_ + j * 32);
        #pragma unroll
        for (int rtk = 0; rtk < 5; ++rtk) {
            const int hr = rtk * 16 + n;
            const int hswz = (hr & 7) << 4;
            bf16x8 af[8];
            #pragma unroll
            for (int j = 0; j < 8; ++j)
                af[j] = *(const bf16x8*)((const char*)hs +
                         ((hr * 512 + (j * 32 + q * 8) * 2) ^ hswz));
            f32x4 aA = {};
            #pragma unroll
            for (int j = 0; j < 8; ++j)
                aA = __builtin_amdgcn_mfma_f32_16x16x32_bf16(af[j], bwa[j], aA, 0, 0, 0);
            #pragma unroll
            for (int idx = 0; idx < 4; ++idx) {
                const int row = rtk * 16 + q * 4 + idx;
                const int rswz = (row & 7) << 4;
                *(unsigned short*)((char*)ks +
                    ((row * 512 + (ct * 16 + n) * 2) ^ rswz)) = f2b_(aA[idx]);
            }
        }
    }
    __syncthreads();   // qs/ks fully written

    // ======== width head + QK^T partial — waves 0..7 only ========
    float wdot = 0.0f;
    f32x4 accS[2] = {};
    if (wave < 8) {
        const int kc0 = half * 128;
        {
            const int hr = 8 + rt8 * 16 + n;
            const int hswz = (hr & 7) << 4;
            #pragma unroll
            for (int jj = 0; jj < 4; ++jj) {
                bf16x8 hv = *(const bf16x8*)((const char*)hs +
                            ((hr * 512 + (kc0 + q * 32 + jj * 8) * 2) ^ hswz));
                float4 wa = *((const float4*)(ww + kc0 + q * 32 + jj * 8));
                float4 wc = *((const float4*)(ww + kc0 + q * 32 + jj * 8 + 4));
                wdot += bf2f_((unsigned short)hv[0]) * wa.x
                      + bf2f_((unsigned short)hv[1]) * wa.y
                      + bf2f_((unsigned short)hv[2]) * wa.z
                      + bf2f_((unsigned short)hv[3]) * wa.w
                      + bf2f_((unsigned short)hv[4]) * wc.x
                      + bf2f_((unsigned short)hv[5]) * wc.y
                      + bf2f_((unsigned short)hv[6]) * wc.z
                      + bf2f_((unsigned short)hv[7]) * wc.w;
            }
        }
        wdot += __shfl_xor(wdot, 16, 64);
        wdot += __shfl_xor(wdot, 32, 64);
        if (half == 1 && q == 0) ws1[rt8 * 16 + n] = wdot;

        {
            const int qrow = rt8 * 16 + n;
            const int qswz = (qrow & 7) << 4;
            bf16x8 qf[4];
            #pragma unroll
            for (int j = 0; j < 4; ++j)
                qf[j] = *(const bf16x8*)((const char*)qs +
                         ((qrow * 512 + (kc0 + q * 8 + j * 32) * 2) ^ qswz));
            #pragma unroll
            for (int h = 0; h < 2; ++h) {
                const int rk = rt8 * 16 + h * 16 + n;
                const int kswz = (rk & 7) << 4;
                #pragma unroll
                for (int j = 0; j < 4; ++j) {
                    bf16x8 kb = *(const bf16x8*)((const char*)ks +
                                ((rk * 512 + (kc0 + q * 8 + j * 32) * 2) ^ kswz));
                    accS[h] = __builtin_amdgcn_mfma_f32_16x16x32_bf16(
                        qf[j], kb, accS[h], 0, 0, 0);
                }
            }
        }
        if (half == 1) {
            *(f32x4*)(sp1 + ((rt8 * 2 + 0) * 64 + lane) * 4) = accS[0];
            *(f32x4*)(sp1 + ((rt8 * 2 + 1) * 64 + lane) * 4) = accS[1];
        }
    }
    __syncthreads();   // sp1 + ws1 staged; qs/ks reads complete

    if (wave < 4) {    // half==0 waves combine + softmax + write P
        accS[0] += *(const f32x4*)(sp1 + ((rt8 * 2 + 0) * 64 + lane) * 4);
        accS[1] += *(const f32x4*)(sp1 + ((rt8 * 2 + 1) * 64 + lane) * 4);
        const float w_n = sigmoidf_(wdot + ws1[rt8 * 16 + n] + wbp[0]) * 8.0f + 0.5f;

        float wd[4];
        #pragma unroll
        for (int r = 0; r < 4; ++r) wd[r] = __shfl(w_n, q * 4 + r, 64);

        float s[2][4];
        #pragma unroll
        for (int h = 0; h < 2; ++h)
            #pragma unroll
            for (int r = 0; r < 4; ++r) {
                int ii = q * 4 + r;
                int c  = h * 16 + n;
                int w  = c - ii;
                float dist = fabsf((float)w - 8.0f);
                float sm = sigmoidf_((wd[r] - dist) * 5.0f);
                float v = accS[h][r] * 0.0625f - (1.0f - sm) * 10000.0f;
                s[h][r] = (w >= 0 && w <= 16) ? v : -3.0e38f;
            }

        float mx[4], sum[4];
        #pragma unroll
        for (int r = 0; r < 4; ++r) mx[r] = fmaxf(s[0][r], s[1][r]);
        #pragma unroll
        for (int m = 1; m < 16; m <<= 1)
            #pragma unroll
            for (int r = 0; r < 4; ++r) mx[r] = fmaxf(mx[r], __shfl_xor(mx[r], m, 64));
        float e[2][4];
        #pragma unroll
        for (int h = 0; h < 2; ++h)
            #pragma unroll
            for (int r = 0; r < 4; ++r) e[h][r] = expf(s[h][r] - mx[r]);
        #pragma unroll
        for (int r = 0; r < 4; ++r) sum[r] = e[0][r] + e[1][r];
        #pragma unroll
        for (int m = 1; m < 16; m <<= 1)
            #pragma unroll
            for (int r = 0; r < 4; ++r) sum[r] += __shfl_xor(sum[r], m, 64);

        // write P (bf16), folding the +Vp[t] residual: +1 at center c == ii+8
        #pragma unroll
        for (int h = 0; h < 2; ++h)
            #pragma unroll
            for (int r = 0; r < 4; ++r) {
                int ii = q * 4 + r, c = h * 16 + n;
                float p = e[h][r] / sum[r];
                if (c == ii + 8) p += 1.0f;
                pb[rt8 * 512 + ii * 32 + c] = f2b_(p);
            }
    }
    __syncthreads();   // pb ready; qs/ks now dead -> vt may overwrite

    // ======== phase B: project Vp (weight rows 512..767) into vt ========
    {
        bf16x8 bwa[8];
        const unsigned short* wa_ = qw + (size_t)(512 + ct * 16 + n) * 256 + q * 8;
        #pragma unroll
        for (int j = 0; j < 8; ++j) bwa[j] = *(const bf16x8*)(wa_ + j * 32);
        #pragma unroll
        for (int rtv = 0; rtv < 5; ++rtv) {
            const int hr = rtv * 16 + n;
            const int hswz = (hr & 7) << 4;
            bf16x8 af[8];
            #pragma unroll
            for (int j = 0; j < 8; ++j)
                af[j] = *(const bf16x8*)((const char*)hs +
                         ((hr * 512 + (j * 32 + q * 8) * 2) ^ hswz));
            f32x4 aA = {};
            #pragma unroll
            for (int j = 0; j < 8; ++j)
                aA = __builtin_amdgcn_mfma_f32_16x16x32_bf16(af[j], bwa[j], aA, 0, 0, 0);
            // Vt[c][r]: 4 consecutive r per lane -> one 8 B store
            ushort4 pA;
            pA.x = f2b_(aA[0]); pA.y = f2b_(aA[1]); pA.z = f2b_(aA[2]); pA.w = f2b_(aA[3]);
            const int rb = rtv * 16 + q * 4;
            *(ushort4*)(vt + (size_t)(ct * 16 + n) * 88 + rb) = pA;
        }
    }
    __syncthreads();   // vt ready

    // ======== PV: wave handles rt = wave&3, ct = (wave>>2)*4 .. +3 ========
    {
        const int rtp = wave & 3;
        const int ctq = wave >> 2;
        bf16x8 pf = *(const bf16x8*)(pb + rtp * 512 + n * 32 + q * 8);
        const int rl = q * 4;                       // even
        const int row0 = t0 + rtp * 16;
        const size_t gbase = seqbase + row0;
        #pragma unroll
        for (int c = 0; c < 4; ++c) {
            const int ctp = ctq * 4 + c;
            bf16x8 vf = *(const bf16x8*)(vt + (ctp * 16 + n) * 88 + rtp * 16 + q * 8);
            f32x4 z = {};
            f32x4 o = __builtin_amdgcn_mfma_f32_16x16x32_bf16(pf, vf, z, 0, 0, 0);
            const int col = ctp * 16 + n;
            float v0 = o[0], v1 = o[1], v2 = o[2], v3 = o[3];
            size_t r0 = (gbase + rl) * CH + col;
            l16o[r0]          = f2b_(v0);
            l16o[r0 + CH]     = f2b_(v1);
            l16o[r0 + 2 * CH] = f2b_(v2);
            l16o[r0 + 3 * CH] = f2b_(v3);
            if (dsB) {
                size_t d0 = ((gbase + rl) >> 1) * CH + col;
                dsB[d0]      = f2b_(0.5f * (v0 + v1));
                dsB[d0 + CH] = f2b_(0.5f * (v2 + v3));
            }
        }
    }
}

// ---------------------------------------------------------------------------
// Mega cooperative kernel: levels 0..3 + global-attn tail + film + final.
// 256 blocks x 1024 threads = exactly 1 block/CU (127 KB LDS) -> co-resident.
// grid.sync() between phases replaces 6 kernel-launch boundaries.
// ---------------------------------------------------------------------------
struct MegaParams {
    const unsigned short* x16g;
    const unsigned short* sw;
    const float* sbias;
    const unsigned short* qw;
    const float* ww;
    const float* wbp;
    unsigned short *l0, *l1, *l2, *l3;
    unsigned short *h1, *h2, *h3;
    const float* query;
    float* partials;
    float* denomP;
    const float* fw;
    const float* fb;
    float* film;
    float* out;
};

__global__ __launch_bounds__(1024, 1) void mega_kernel(MegaParams p)
{
    __shared__ __align__(16) char smem[127232];
    cg::grid_group grid = cg::this_grid();
    const int blk = blockIdx.x;
    const int tid = threadIdx.x;

    // ---- level 0 (stem fused), logical grid 256 ----
    do_level<1>(smem, blk, 256, nullptr, p.x16g, p.sw, p.sbias, p.qw,
                p.ww, p.wbp, p.l0, p.h1, L_SEQ);
    grid.sync();
    // ---- level 1, logical grid 128 ----
    if (blk < 128)
        do_level<0>(smem, blk, 128, p.h1, p.x16g, p.sw, p.sbias, p.qw,
                    p.ww, p.wbp, p.l1, p.h2, L_SEQ >> 1);
    grid.sync();
    // ---- level 2, logical grid 64 ----
    if (blk < 64)
        do_level<0>(smem, blk, 64, p.h2, p.x16g, p.sw, p.sbias, p.qw,
                    p.ww, p.wbp, p.l2, p.h3, L_SEQ >> 2);
    grid.sync();
    // ---- level 3, logical grid 32 ----
    if (blk < 32)
        do_level<0>(smem, blk, 32, p.h3, p.x16g, p.sw, p.sbias, p.qw,
                    p.ww, p.wbp, p.l3, nullptr, L_SEQ >> 3);
    grid.sync();

    // ---- tail: blocks 0..127 = (chunk = blk&63, b = blk>>6) ----
    if (blk < 128) {
        float* eS = (float*)smem;
        const int chunk = blk & 63, b = blk >> 6;
        const int t0 = chunk * 128;
        const unsigned short* levp[4] = {p.l0, p.l1, p.l2, p.l3};

        const int w = tid >> 6, lane = tid & 63;
        const int lev = lane >> 4, c0 = (lane & 15) * 16;
        const unsigned short* lpbase = levp[lev] + (size_t)b * (L_SEQ >> lev) * CH;
        const float* qp = p.query + lev * CH + c0;
        float4 q0 = *(const float4*)(qp);
        float4 q1 = *(const float4*)(qp + 4);
        float4 q2 = *(const float4*)(qp + 8);
        float4 q3 = *(const float4*)(qp + 12);
        #pragma unroll
        for (int j = 0; j < 8; ++j) {
            int t = t0 + w * 8 + j;
            const unsigned short* pp = lpbase + (size_t)(t >> lev) * CH + c0;
            float4 h0 = ldb4_(pp), h1 = ldb4_(pp + 4), h2 = ldb4_(pp + 8), h3 = ldb4_(pp + 12);
            float part = h0.x * q0.x + h0.y * q0.y + h0.z * q0.z + h0.w * q0.w
                       + h1.x * q1.x + h1.y * q1.y + h1.z * q1.z + h1.w * q1.w
                       + h2.x * q2.x + h2.y * q2.y + h2.z * q2.z + h2.w * q2.w
                       + h3.x * q3.x + h3.y * q3.y + h3.z * q3.z + h3.w * q3.w;
            #pragma unroll
            for (int m = 1; m < 64; m <<= 1) part += __shfl_xor(part, m, 64);
            if (lane == 0) eS[w * 8 + j] = expf(part);
        }
        __syncthreads();

        if (tid == 0) {
            float ds = 0.0f;
            #pragma unroll 8
            for (int i = 0; i < 128; ++i) ds += eS[i];
            p.denomP[b * 64 + chunk] = ds;
        }

        const int dlev = tid >> 8, c = tid & 255;
        const unsigned short* lp = levp[dlev] + (size_t)b * (L_SEQ >> dlev) * CH;
        float acc = 0.0f;
        #pragma unroll 4
        for (int t = t0; t < t0 + 128; ++t)
            acc += eS[t - t0] * bf2f_(lp[(size_t)(t >> dlev) * CH + c]);
        p.partials[(size_t)(b * 64 + chunk) * 1024 + tid] = acc;
    }
    grid.sync();

    // ---- film: blocks 0..31, 16 waves -> j = blk*16 + wave ----
    if (blk < 32) {
        float* ctxS = (float*)smem;               // 2048 floats
        float den[2];
        #pragma unroll
        for (int b = 0; b < 2; ++b) {
            float d = 0.0f;
            #pragma unroll
            for (int c = 0; c < 64; ++c) d += p.denomP[b * 64 + c];
            den[b] = d;
        }
        #pragma unroll
        for (int v = 0; v < 2; ++v) {
            const int idx = v * 1024 + tid;       // 0..2047
            const int b = idx >> 10, d = idx & 1023;
            float acc = 0.0f;
            #pragma unroll
            for (int c = 0; c < 64; ++c)
                acc += p.partials[(size_t)(b * 64 + c) * 1024 + d];
            ctxS[idx] = acc / den[b];
        }
        __syncthreads();

        const int lane = tid & 63;
        const int j = blk * 16 + (tid >> 6);      // 0..511
        float acc0 = 0.0f, acc1 = 0.0f;
        #pragma unroll
        for (int r = 0; r < 4; ++r) {
            float4 w4 = *((const float4*)(p.fw + (size_t)j * 1024 + r * 256) + lane);
            float4 c0 = *((const float4*)(ctxS + r * 256) + lane);
            float4 c1 = *((const float4*)(ctxS + 1024 + r * 256) + lane);
            acc0 += w4.x * c0.x + w4.y * c0.y + w4.z * c0.z + w4.w * c0.w;
            acc1 += w4.x * c1.x + w4.y * c1.y + w4.z * c1.z + w4.w * c1.w;
        }
        #pragma unroll
        for (int m = 1; m < 64; m <<= 1) {
            acc0 += __shfl_xor(acc0, m, 64);
            acc1 += __shfl_xor(acc1, m, 64);
        }
        if (lane == 0) {
            float b = p.fb[j];
            p.film[j] = acc0 + b;
            p.film[512 + j] = acc1 + b;
        }
    }
    grid.sync();

    // ---- final: out = l0 * (1 + scale) + bias; grid-strided, 4 f4/thread --
    #pragma unroll
    for (int it = 0; it < 4; ++it) {
        size_t n4 = ((size_t)it * 262144 + (size_t)blk * 1024 + tid) * 4;
        int c = (int)(n4 & (CH - 1));
        int b = (int)(n4 >> 21);  // L*C = 2^21
        float4 h = ldb4_(p.l0 + n4);
        const float* fs = p.film + b * 512;
        float4 o;
        o.x = h.x * (1.0f + fs[c + 0]) + fs[256 + c + 0];
        o.y = h.y * (1.0f + fs[c + 1]) + fs[256 + c + 1];
        o.z = h.z * (1.0f + fs[c + 2]) + fs[256 + c + 2];
        o.w = h.w * (1.0f + fs[c + 3]) + fs[256 + c + 3];
        *(float4*)(p.out + n4) = o;
    }
}

extern "C" void kernel_launch(void* const* d_in, const int* in_sizes, int n_in,
                              void* d_out, int out_size, void* d_ws, size_t ws_size,
                              hipStream_t stream) {
    const float* x       = (const float*)d_in[0];
    const float* stem_w  = (const float*)d_in[1];
    const float* stem_b  = (const float*)d_in[2];
    const float* qkv_w   = (const float*)d_in[3];
    const float* width_w = (const float*)d_in[4];
    const float* width_b = (const float*)d_in[5];
    const float* out_w   = (const float*)d_in[6];
    const float* query   = (const float*)d_in[7];
    const float* film_w  = (const float*)d_in[8];
    const float* film_b  = (const float*)d_in[9];
    float* out = (float*)d_out;
    float* ws  = (float*)d_ws;

    // ---- workspace layout (fp32 region then bf16 region) ----
    float* partials = ws;                       // 131,072
    float* denomP   = partials + 131072;        // 128
    float* ctx      = denomP + 128;             // 2,048 (unused)
    float* film     = ctx + 2048;               // 1,024
    unsigned short* x16g  = (unsigned short*)(film + 1024);  // 256 guard + 4,194,304
    unsigned short* h16_0 = x16g + 4194560;     // 4,194,304 (unused now)
    unsigned short* h16_1 = h16_0 + 4194304;    // 2,097,152
    unsigned short* h16_2 = h16_1 + 2097152;    // 1,048,576
    unsigned short* h16_3 = h16_2 + 1048576;    //   524,288
    unsigned short* qkv16 = h16_3 + 524288;     // 12,582,912 (reserved, unused)
    unsigned short* ov16  = qkv16 + 12582912;   // 4,194,304 (reserved, unused)
    unsigned short* l16_0 = ov16 + 4194304;     // 4,194,304
    unsigned short* l16_1 = l16_0 + 4194304;    // 2,097,152
    unsigned short* l16_2 = l16_1 + 2097152;    // 1,048,576
    unsigned short* l16_3 = l16_2 + 1048576;    //   524,288
    unsigned short* qw16  = l16_3 + 524288;     //   196,608
    unsigned short* ow16  = qw16 + 196608;      //    65,536 (reserved, unused)
    unsigned short* sw16  = ow16 + 65536;       //   131,072
    (void)h16_0; (void)qkv16; (void)ov16; (void)ow16;

    // ---- fused prep (guard + x16 + q/k weights + stem) + Vp weight fold ----
    prep_kernel<<<NPREP_BLOCKS + 256, 256, 0, stream>>>(
        x, qkv_w, out_w, stem_w, x16g, qw16, sw16);

    // ---- everything else: ONE cooperative kernel (levels + tail + film +
    //      final), 256 blocks x 1024 threads, grid.sync between phases ----
    MegaParams p;
    p.x16g = x16g; p.sw = sw16; p.sbias = stem_b; p.qw = qw16;
    p.ww = width_w; p.wbp = width_b;
    p.l0 = l16_0; p.l1 = l16_1; p.l2 = l16_2; p.l3 = l16_3;
    p.h1 = h16_1; p.h2 = h16_2; p.h3 = h16_3;
    p.query = query; p.partials = partials; p.denomP = denomP;
    p.fw = film_w; p.fb = film_b; p.film = film; p.out = out;

    void* args[] = { &p };
    hipLaunchCooperativeKernel((const void*)mega_kernel, dim3(256), dim3(1024),
                               args, 0, stream);
}

// Round 12
// 216.572 us; speedup vs baseline: 1.9468x; 1.9468x over previous
//
#include <hip/hip_runtime.h>
#include <math.h>

#define L_SEQ 8192
#define B_SZ  2
#define CH    256
#define NLEV  4

typedef __attribute__((ext_vector_type(8))) short bf16x8;
typedef __attribute__((ext_vector_type(4))) float f32x4;

static __device__ __forceinline__ float sigmoidf_(float x) {
    return 1.0f / (1.0f + expf(-x));
}

// bf16 (stored as ushort) <-> fp32 helpers. bf2f is exact; f2b is RNE.
static __device__ __forceinline__ float bf2f_(unsigned short u) {
    union { unsigned int ui; float f; } x;
    x.ui = ((unsigned int)u) << 16;
    return x.f;
}
static __device__ __forceinline__ unsigned short f2b_(float f) {
    union { float f; unsigned int u; } x;
    x.f = f;
    unsigned int lsb = (x.u >> 16) & 1u;
    unsigned int r = x.u + 0x7fffu + lsb;
    return (unsigned short)(r >> 16);
}
static __device__ __forceinline__ float4 ldb4_(const unsigned short* p) {
    ushort4 u = *(const ushort4*)p;
    return make_float4(bf2f_(u.x), bf2f_(u.y), bf2f_(u.z), bf2f_(u.w));
}

// ---------------------------------------------------------------------------
// Fused fp32->bf16 prep + weight fold, one launch:
//   blocks [0, 17409):   guard row + x16 + qkv_w rows 0..511 + stem_w
//   blocks [17409, 17665): W'[c][j] = sum_k out_w[c][k]*qkv_w[512+k][j]
//     -> qw16 rows 512..767 (bf16).  Vp = v @ out_w^T, so attention's PV
//     output IS the level output: (P@V_win + v)@ow^T == P@Vp_win + Vp.
// ---------------------------------------------------------------------------
#define NPREP_BLOCKS 17409
__global__ __launch_bounds__(256) void prep_kernel(
    const float* __restrict__ x, const float* __restrict__ qkv_w,
    const float* __restrict__ out_w, const float* __restrict__ stem_w,
    unsigned short* __restrict__ x16g, unsigned short* __restrict__ qw16,
    unsigned short* __restrict__ sw16)
{
    __shared__ float owr[256];
    if (blockIdx.x >= NPREP_BLOCKS) {
        const int c = blockIdx.x - NPREP_BLOCKS, j = threadIdx.x;
        owr[j] = out_w[(size_t)c * 256 + j];
        __syncthreads();
        float acc = 0.0f;
        #pragma unroll 8
        for (int k = 0; k < 256; ++k)
            acc += owr[k] * qkv_w[(size_t)(512 + k) * 256 + j];
        qw16[(size_t)(512 + c) * 256 + j] = f2b_(acc);
        return;
    }
    int i = blockIdx.x * 256 + threadIdx.x;
    if (i < 256) { x16g[i] = 0; return; }           // guard row of zeros
    i -= 256;
    if (i < 4194304) { x16g[256 + i] = f2b_(x[i]); return; }
    i -= 4194304;
    if (i < 131072) { qw16[i] = f2b_(qkv_w[i]); return; }  // q,k rows only
    i -= 131072;
    {   // stem W: (256,512); k<256 -> tap0, else tap1
        int k = i & 511, nn = i >> 9;
        float v = (k < 256) ? stem_w[(size_t)nn * 512 + k * 2]
                            : stem_w[(size_t)nn * 512 + (k - 256) * 2 + 1];
        sw16[i] = f2b_(v);
    }
}

// ---------------------------------------------------------------------------
// FULLY fused level kernel, 64-row blocks, 16 WAVES (1024 thr) — round-10
// structure with two latency fixes:
//  (a) the softmax barrier is MERGED into the Vp barrier: after the sp1
//      barrier qs/ks are dead (all QK reads precede it), so waves 4..15
//      start the Vp projection (vt aliases qs/ks) concurrently with waves
//      0..3's softmax; softmax touches only sp1/ws1/pb (disjoint regions).
//  (b) s_setprio(1) around MFMA clusters (T5: wave role diversity).
// All MFMA chains / rounding points identical to round 10 -> bitwise-same.
//
// LDS plan (127,232 B -> 1 block/CU, 4 waves/SIMD):
//   hs [80][256]  @0       : H halo (swizzled)
//   xs [81][256]  @40960   : x halo for stem (STEM=1; dead before qs/ks)
//   qs [64 rows]  @40960   : q (bf16, XOR-swizzled)
//   ks [80 rows]  @73728   : k (bf16, XOR-swizzled)
//   vt [256][88]  @40960   : Vp^T — aliases qs/ks after QK^T is done
//   pb 4x[16][32] @114688  : P per row tile
//   sp1           @118784  : half-1 partial S (fp32)
//   ws1           @126976  : half-1 width partials
// ---------------------------------------------------------------------------
template<int STEM>
__global__ __launch_bounds__(1024, 1) void level_fused_kernel(
    const unsigned short* __restrict__ h16in, const unsigned short* __restrict__ x16g,
    const unsigned short* __restrict__ sw, const float* __restrict__ sbias,
    const unsigned short* __restrict__ qw,
    const float* __restrict__ ww, const float* __restrict__ wbp,
    unsigned short* __restrict__ l16o, unsigned short* __restrict__ dsB, int l)
{
    __shared__ __align__(16) char smem[127232];
    unsigned short* hs = (unsigned short*)smem;              // 40960 B
    unsigned short* xs = (unsigned short*)(smem + 40960);    // 41472 B (alias)
    unsigned short* qs = (unsigned short*)(smem + 40960);    // 32768 B
    unsigned short* ks = (unsigned short*)(smem + 73728);    // 40960 B
    unsigned short* vt = (unsigned short*)(smem + 40960);    // 45056 B (alias)
    unsigned short* pb = (unsigned short*)(smem + 114688);   //  4096 B
    float* sp1 = (float*)(smem + 118784);                    //  8192 B
    float* ws1 = (float*)(smem + 126976);                    //   256 B

    const int tid  = threadIdx.x;
    const int wave = tid >> 6;        // 0..15
    const int lane = tid & 63;
    const int rt8  = wave & 3;        // QK/softmax row tile 0..3 (waves 0..7)
    const int half = (wave >> 2) & 1; // QK channel half (waves 0..7)
    const int q    = lane >> 4;
    const int n    = lane & 15;
    const int ct   = wave;            // projection col tile 0..15

    // XCD-aware swizzle (grid is always a multiple of 8)
    int bid = blockIdx.x;
    const int cpx = gridDim.x >> 3;
    bid = (bid & 7) * cpx + (bid >> 3);

    const int bps = l >> 6;
    const int b  = bid / bps;
    const int t0 = (bid % bps) << 6;
    const size_t seqbase = (size_t)b * l;

    if constexpr (STEM) {
        // ---- stage x halo: 81 rows (gx = t0-9 .. t0+71), pre-swizzled src --
        #pragma unroll
        for (int i = 0; i < 3; ++i) {
            const int task = i * 1024 + tid;
            if (task < 2592) {
                const int r = task >> 5, ch = task & 31;
                const int gx = t0 - 9 + r;
                const unsigned short* src = (gx >= 0 && gx < l)
                    ? x16g + ((size_t)(seqbase + gx) + 1) * 256 + ((ch ^ (r & 7)) << 3)
                    : x16g;                       // guard zeros
                __builtin_amdgcn_global_load_lds(
                    (const __attribute__((address_space(1))) void*)src,
                    (__attribute__((address_space(3))) void*)
                        (xs + (size_t)(i * 1024 + (tid & ~63)) * 8),
                    16, 0, 0);
            }
        }
        __syncthreads();

        // ---- in-block stem GEMM: h rows 0..79 (halo); wave owns ct ----
        f32x4 accA[5] = {};
        __builtin_amdgcn_s_setprio(1);
        #pragma unroll
        for (int pass = 0; pass < 2; ++pass) {
            bf16x8 wA[8];
            const unsigned short* wa_ = sw + (size_t)(ct * 16 + n) * 512 + pass * 256 + q * 8;
            #pragma unroll
            for (int j = 0; j < 8; ++j) wA[j] = *(const bf16x8*)(wa_ + j * 32);
            #pragma unroll
            for (int rtile = 0; rtile < 5; ++rtile) {
                const int xr = rtile * 16 + n + pass;
                const int xswz = (xr & 7) << 4;
                bf16x8 af[8];
                #pragma unroll
                for (int j = 0; j < 8; ++j)
                    af[j] = *(const bf16x8*)((const char*)xs +
                             ((xr * 512 + (j * 32 + q * 8) * 2) ^ xswz));
                #pragma unroll
                for (int j = 0; j < 8; ++j)
                    accA[rtile] = __builtin_amdgcn_mfma_f32_16x16x32_bf16(
                        af[j], wA[j], accA[rtile], 0, 0, 0);
            }
        }
        __builtin_amdgcn_s_setprio(0);
        const float bA = sbias[ct * 16 + n];
        #pragma unroll
        for (int rtile = 0; rtile < 5; ++rtile)
            #pragma unroll
            for (int idx = 0; idx < 4; ++idx) {
                const int row = rtile * 16 + q * 4 + idx;     // 0..79
                const int growh = t0 - 8 + row;
                const int rswz = (row & 7) << 4;
                const bool ok = (growh >= 0 && growh < l);
                *(unsigned short*)((char*)hs +
                    ((row * 512 + (ct * 16 + n) * 2) ^ rswz)) =
                        ok ? f2b_(accA[rtile][idx] + bA) : (unsigned short)0;
            }
        __syncthreads();   // hs computed (xs now dead -> qs/ks may overwrite)
    } else {
        // ---- stage H halo (80 rows x 256 ch); source pre-swizzled ----
        #pragma unroll
        for (int i = 0; i < 3; ++i) {
            const int task = i * 1024 + tid;
            if (task < 2560) {
                const int r = task >> 5, ch = task & 31;
                const int grow = t0 - 8 + r;
                const unsigned short* src = (grow >= 0 && grow < l)
                    ? h16in + (seqbase + grow) * 256 + ((ch ^ (r & 7)) << 3)
                    : x16g;                       // 512 B of zeros (guard)
                __builtin_amdgcn_global_load_lds(
                    (const __attribute__((address_space(1))) void*)src,
                    (__attribute__((address_space(3))) void*)
                        (hs + (size_t)(i * 1024 + (tid & ~63)) * 8),
                    16, 0, 0);
            }
        }
        __syncthreads();
    }

    // ======== phase A: project q,k — wave owns ONE col-tile ct ========
    {   // ---- q (weight rows 0..255) -> qs rows 0..63 ----
        bf16x8 bwa[8];
        const unsigned short* wa_ = qw + (size_t)(ct * 16 + n) * 256 + q * 8;
        #pragma unroll
        for (int j = 0; j < 8; ++j) bwa[j] = *(const bf16x8*)(wa_ + j * 32);
        __builtin_amdgcn_s_setprio(1);
        #pragma unroll
        for (int rtq = 0; rtq < 4; ++rtq) {
            const int hr = 8 + rtq * 16 + n;
            const int hswz = (hr & 7) << 4;
            bf16x8 af[8];
            #pragma unroll
            for (int j = 0; j < 8; ++j)
                af[j] = *(const bf16x8*)((const char*)hs +
                         ((hr * 512 + (j * 32 + q * 8) * 2) ^ hswz));
            f32x4 aA = {};
            #pragma unroll
            for (int j = 0; j < 8; ++j)
                aA = __builtin_amdgcn_mfma_f32_16x16x32_bf16(af[j], bwa[j], aA, 0, 0, 0);
            #pragma unroll
            for (int idx = 0; idx < 4; ++idx) {
                const int row = rtq * 16 + q * 4 + idx;
                const int rswz = (row & 7) << 4;
                *(unsigned short*)((char*)qs +
                    ((row * 512 + (ct * 16 + n) * 2) ^ rswz)) = f2b_(aA[idx]);
            }
        }
        __builtin_amdgcn_s_setprio(0);
    }
    {   // ---- k (weight rows 256..511) -> ks halo rows 0..79 ----
        bf16x8 bwa[8];
        const unsigned short* wa_ = qw + (size_t)(256 + ct * 16 + n) * 256 + q * 8;
        #pragma unroll
        for (int j = 0; j < 8; ++j) bwa[j] = *(const bf16x8*)(wa_ + j * 32);
        __builtin_amdgcn_s_setprio(1);
        #pragma unroll
        for (int rtk = 0; rtk < 5; ++rtk) {
            const int hr = rtk * 16 + n;
            const int hswz = (hr & 7) << 4;
            bf16x8 af[8];
            #pragma unroll
            for (int j = 0; j < 8; ++j)
                af[j] = *(const bf16x8*)((const char*)hs +
                         ((hr * 512 + (j * 32 + q * 8) * 2) ^ hswz));
            f32x4 aA = {};
            #pragma unroll
            for (int j = 0; j < 8; ++j)
                aA = __builtin_amdgcn_mfma_f32_16x16x32_bf16(af[j], bwa[j], aA, 0, 0, 0);
            #pragma unroll
            for (int idx = 0; idx < 4; ++idx) {
                const int row = rtk * 16 + q * 4 + idx;
                const int rswz = (row & 7) << 4;
                *(unsigned short*)((char*)ks +
                    ((row * 512 + (ct * 16 + n) * 2) ^ rswz)) = f2b_(aA[idx]);
            }
        }
        __builtin_amdgcn_s_setprio(0);
    }
    __syncthreads();   // qs/ks fully written

    // ======== width head + QK^T partial — waves 0..7 only ========
    float wdot = 0.0f;
    f32x4 accS[2] = {};
    if (wave < 8) {
        const int kc0 = half * 128;
        {
            const int hr = 8 + rt8 * 16 + n;
            const int hswz = (hr & 7) << 4;
            #pragma unroll
            for (int jj = 0; jj < 4; ++jj) {
                bf16x8 hv = *(const bf16x8*)((const char*)hs +
                            ((hr * 512 + (kc0 + q * 32 + jj * 8) * 2) ^ hswz));
                float4 wa = *((const float4*)(ww + kc0 + q * 32 + jj * 8));
                float4 wc = *((const float4*)(ww + kc0 + q * 32 + jj * 8 + 4));
                wdot += bf2f_((unsigned short)hv[0]) * wa.x
                      + bf2f_((unsigned short)hv[1]) * wa.y
                      + bf2f_((unsigned short)hv[2]) * wa.z
                      + bf2f_((unsigned short)hv[3]) * wa.w
                      + bf2f_((unsigned short)hv[4]) * wc.x
                      + bf2f_((unsigned short)hv[5]) * wc.y
                      + bf2f_((unsigned short)hv[6]) * wc.z
                      + bf2f_((unsigned short)hv[7]) * wc.w;
            }
        }
        wdot += __shfl_xor(wdot, 16, 64);
        wdot += __shfl_xor(wdot, 32, 64);
        if (half == 1 && q == 0) ws1[rt8 * 16 + n] = wdot;

        {
            const int qrow = rt8 * 16 + n;
            const int qswz = (qrow & 7) << 4;
            bf16x8 qf[4];
            #pragma unroll
            for (int j = 0; j < 4; ++j)
                qf[j] = *(const bf16x8*)((const char*)qs +
                         ((qrow * 512 + (kc0 + q * 8 + j * 32) * 2) ^ qswz));
            __builtin_amdgcn_s_setprio(1);
            #pragma unroll
            for (int h = 0; h < 2; ++h) {
                const int rk = rt8 * 16 + h * 16 + n;
                const int kswz = (rk & 7) << 4;
                #pragma unroll
                for (int j = 0; j < 4; ++j) {
                    bf16x8 kb = *(const bf16x8*)((const char*)ks +
                                ((rk * 512 + (kc0 + q * 8 + j * 32) * 2) ^ kswz));
                    accS[h] = __builtin_amdgcn_mfma_f32_16x16x32_bf16(
                        qf[j], kb, accS[h], 0, 0, 0);
                }
            }
            __builtin_amdgcn_s_setprio(0);
        }
        if (half == 1) {
            *(f32x4*)(sp1 + ((rt8 * 2 + 0) * 64 + lane) * 4) = accS[0];
            *(f32x4*)(sp1 + ((rt8 * 2 + 1) * 64 + lane) * 4) = accS[1];
        }
    }
    __syncthreads();   // sp1 + ws1 staged; ALL qs/ks reads complete

    // ======== softmax (waves 0..3) CONCURRENT with Vp start (waves 4..15) --
    if (wave < 4) {    // half==0 waves combine + softmax + write P
        accS[0] += *(const f32x4*)(sp1 + ((rt8 * 2 + 0) * 64 + lane) * 4);
        accS[1] += *(const f32x4*)(sp1 + ((rt8 * 2 + 1) * 64 + lane) * 4);
        const float w_n = sigmoidf_(wdot + ws1[rt8 * 16 + n] + wbp[0]) * 8.0f + 0.5f;

        float wd[4];
        #pragma unroll
        for (int r = 0; r < 4; ++r) wd[r] = __shfl(w_n, q * 4 + r, 64);

        float s[2][4];
        #pragma unroll
        for (int h = 0; h < 2; ++h)
            #pragma unroll
            for (int r = 0; r < 4; ++r) {
                int ii = q * 4 + r;
                int c  = h * 16 + n;
                int w  = c - ii;
                float dist = fabsf((float)w - 8.0f);
                float sm = sigmoidf_((wd[r] - dist) * 5.0f);
                float v = accS[h][r] * 0.0625f - (1.0f - sm) * 10000.0f;
                s[h][r] = (w >= 0 && w <= 16) ? v : -3.0e38f;
            }

        float mx[4], sum[4];
        #pragma unroll
        for (int r = 0; r < 4; ++r) mx[r] = fmaxf(s[0][r], s[1][r]);
        #pragma unroll
        for (int m = 1; m < 16; m <<= 1)
            #pragma unroll
            for (int r = 0; r < 4; ++r) mx[r] = fmaxf(mx[r], __shfl_xor(mx[r], m, 64));
        float e[2][4];
        #pragma unroll
        for (int h = 0; h < 2; ++h)
            #pragma unroll
            for (int r = 0; r < 4; ++r) e[h][r] = expf(s[h][r] - mx[r]);
        #pragma unroll
        for (int r = 0; r < 4; ++r) sum[r] = e[0][r] + e[1][r];
        #pragma unroll
        for (int m = 1; m < 16; m <<= 1)
            #pragma unroll
            for (int r = 0; r < 4; ++r) sum[r] += __shfl_xor(sum[r], m, 64);

        // write P (bf16), folding the +Vp[t] residual: +1 at center c == ii+8
        #pragma unroll
        for (int h = 0; h < 2; ++h)
            #pragma unroll
            for (int r = 0; r < 4; ++r) {
                int ii = q * 4 + r, c = h * 16 + n;
                float p = e[h][r] / sum[r];
                if (c == ii + 8) p += 1.0f;
                pb[rt8 * 512 + ii * 32 + c] = f2b_(p);
            }
    }
    // NO barrier here: waves 4..15 proceed straight into Vp (vt aliases
    // qs/ks which are dead; softmax touches only sp1/ws1/pb).

    // ======== phase B: project Vp (weight rows 512..767) into vt ========
    {
        bf16x8 bwa[8];
        const unsigned short* wa_ = qw + (size_t)(512 + ct * 16 + n) * 256 + q * 8;
        #pragma unroll
        for (int j = 0; j < 8; ++j) bwa[j] = *(const bf16x8*)(wa_ + j * 32);
        __builtin_amdgcn_s_setprio(1);
        #pragma unroll
        for (int rtv = 0; rtv < 5; ++rtv) {
            const int hr = rtv * 16 + n;
            const int hswz = (hr & 7) << 4;
            bf16x8 af[8];
            #pragma unroll
            for (int j = 0; j < 8; ++j)
                af[j] = *(const bf16x8*)((const char*)hs +
                         ((hr * 512 + (j * 32 + q * 8) * 2) ^ hswz));
            f32x4 aA = {};
            #pragma unroll
            for (int j = 0; j < 8; ++j)
                aA = __builtin_amdgcn_mfma_f32_16x16x32_bf16(af[j], bwa[j], aA, 0, 0, 0);
            // Vt[c][r]: 4 consecutive r per lane -> one 8 B store
            ushort4 pA;
            pA.x = f2b_(aA[0]); pA.y = f2b_(aA[1]); pA.z = f2b_(aA[2]); pA.w = f2b_(aA[3]);
            const int rb = rtv * 16 + q * 4;
            *(ushort4*)(vt + (size_t)(ct * 16 + n) * 88 + rb) = pA;
        }
        __builtin_amdgcn_s_setprio(0);
    }
    __syncthreads();   // vt + pb ready (single merged barrier)

    // ======== PV: wave handles rt = wave&3, ct = (wave>>2)*4 .. +3 ========
    {
        const int rtp = wave & 3;
        const int ctq = wave >> 2;
        bf16x8 pf = *(const bf16x8*)(pb + rtp * 512 + n * 32 + q * 8);
        const int rl = q * 4;                       // even
        const int row0 = t0 + rtp * 16;
        const size_t gbase = seqbase + row0;
        #pragma unroll
        for (int c = 0; c < 4; ++c) {
            const int ctp = ctq * 4 + c;
            bf16x8 vf = *(const bf16x8*)(vt + (ctp * 16 + n) * 88 + rtp * 16 + q * 8);
            f32x4 z = {};
            f32x4 o = __builtin_amdgcn_mfma_f32_16x16x32_bf16(pf, vf, z, 0, 0, 0);
            const int col = ctp * 16 + n;
            float v0 = o[0], v1 = o[1], v2 = o[2], v3 = o[3];
            size_t r0 = (gbase + rl) * CH + col;
            l16o[r0]          = f2b_(v0);
            l16o[r0 + CH]     = f2b_(v1);
            l16o[r0 + 2 * CH] = f2b_(v2);
            l16o[r0 + 3 * CH] = f2b_(v3);
            if (dsB) {
                size_t d0 = ((gbase + rl) >> 1) * CH + col;
                dsB[d0]      = f2b_(0.5f * (v0 + v1));
                dsB[d0 + CH] = f2b_(0.5f * (v2 + v3));
            }
        }
    }
}

// ---------------------------------------------------------------------------
// Fused global-attention tail: per block (chunk of 128 t's, batch b):
//   pass 1: e[t] = exp(concat[t]·query)  (unnormalized softmax — |s| small)
//   pass 2: partials[d] = sum_t e[t]*concat[t][d]; denomP = sum_t e[t]
// grid (64, B), block 1024.
// ---------------------------------------------------------------------------
__global__ __launch_bounds__(1024) void tail_ctx_kernel(
    const unsigned short* __restrict__ l0, const unsigned short* __restrict__ l1,
    const unsigned short* __restrict__ l2, const unsigned short* __restrict__ l3,
    const float* __restrict__ query, float* __restrict__ partials,
    float* __restrict__ denomP)
{
    __shared__ float eS[128];
    const int tid = threadIdx.x;
    const int chunk = blockIdx.x, b = blockIdx.y;
    const int t0 = chunk * 128;
    const unsigned short* levp[4] = {l0, l1, l2, l3};

    // ---- pass 1: wave w computes e for t = t0 + w*8 + j ----
    const int w = tid >> 6, lane = tid & 63;
    const int lev = lane >> 4, c0 = (lane & 15) * 16;
    const unsigned short* lpbase = levp[lev] + (size_t)b * (L_SEQ >> lev) * CH;
    const float* qp = query + lev * CH + c0;
    float4 q0 = *(const float4*)(qp);
    float4 q1 = *(const float4*)(qp + 4);
    float4 q2 = *(const float4*)(qp + 8);
    float4 q3 = *(const float4*)(qp + 12);
    #pragma unroll
    for (int j = 0; j < 8; ++j) {
        int t = t0 + w * 8 + j;
        const unsigned short* p = lpbase + (size_t)(t >> lev) * CH + c0;
        float4 h0 = ldb4_(p), h1 = ldb4_(p + 4), h2 = ldb4_(p + 8), h3 = ldb4_(p + 12);
        float part = h0.x * q0.x + h0.y * q0.y + h0.z * q0.z + h0.w * q0.w
                   + h1.x * q1.x + h1.y * q1.y + h1.z * q1.z + h1.w * q1.w
                   + h2.x * q2.x + h2.y * q2.y + h2.z * q2.z + h2.w * q2.w
                   + h3.x * q3.x + h3.y * q3.y + h3.z * q3.z + h3.w * q3.w;
        #pragma unroll
        for (int m = 1; m < 64; m <<= 1) part += __shfl_xor(part, m, 64);
        if (lane == 0) eS[w * 8 + j] = expf(part);
    }
    __syncthreads();

    if (tid == 0) {
        float ds = 0.0f;
        #pragma unroll 8
        for (int i = 0; i < 128; ++i) ds += eS[i];
        denomP[b * 64 + chunk] = ds;
    }

    // ---- pass 2: weighted accumulation (rows are L2-hot from pass 1) ----
    const int dlev = tid >> 8, c = tid & 255;
    const unsigned short* lp = levp[dlev] + (size_t)b * (L_SEQ >> dlev) * CH;
    float acc = 0.0f;
    #pragma unroll 4
    for (int t = t0; t < t0 + 128; ++t)
        acc += eS[t - t0] * bf2f_(lp[(size_t)(t >> dlev) * CH + c]);
    partials[(size_t)(b * 64 + chunk) * 1024 + tid] = acc;
}

// ---------------------------------------------------------------------------
// film kernel with the ctx reduction folded in: each block cooperatively
// recomputes ctx (ascending-chunk sum / denom — bitwise-identical to the old
// ctx_reduce) into LDS, then runs the unchanged film math from LDS.
// grid 128, block 256 (4 waves, one j per wave).
// ---------------------------------------------------------------------------
__global__ __launch_bounds__(256) void film_kernel(
    const float* __restrict__ partials, const float* __restrict__ denomP,
    const float* __restrict__ fw, const float* __restrict__ fb,
    float* __restrict__ film)
{
    __shared__ float ctxS[2048];
    const int tid = threadIdx.x;

    float den[2];
    #pragma unroll
    for (int b = 0; b < 2; ++b) {
        float d = 0.0f;
        #pragma unroll
        for (int c = 0; c < 64; ++c) d += denomP[b * 64 + c];
        den[b] = d;
    }
    #pragma unroll
    for (int v = 0; v < 8; ++v) {
        const int idx = v * 256 + tid;            // 0..2047
        const int b = idx >> 10, d = idx & 1023;
        float acc = 0.0f;
        #pragma unroll
        for (int c = 0; c < 64; ++c)
            acc += partials[(size_t)(b * 64 + c) * 1024 + d];
        ctxS[idx] = acc / den[b];
    }
    __syncthreads();

    const int lane = tid & 63;
    const int j = blockIdx.x * 4 + (tid >> 6);    // 0..511
    float acc0 = 0.0f, acc1 = 0.0f;
    #pragma unroll
    for (int r = 0; r < 4; ++r) {
        float4 w4 = *((const float4*)(fw + (size_t)j * 1024 + r * 256) + lane);
        float4 c0 = *((const float4*)(ctxS + r * 256) + lane);
        float4 c1 = *((const float4*)(ctxS + 1024 + r * 256) + lane);
        acc0 += w4.x * c0.x + w4.y * c0.y + w4.z * c0.z + w4.w * c0.w;
        acc1 += w4.x * c1.x + w4.y * c1.y + w4.z * c1.z + w4.w * c1.w;
    }
    #pragma unroll
    for (int m = 1; m < 64; m <<= 1) {
        acc0 += __shfl_xor(acc0, m, 64);
        acc1 += __shfl_xor(acc1, m, 64);
    }
    if (lane == 0) {
        float b = fb[j];
        film[j] = acc0 + b;
        film[512 + j] = acc1 + b;
    }
}

// out = l16_0 * (1 + scale_f) + bias_f, 4 elem/thread (ushort4 -> float4)
__global__ void final_kernel(const unsigned short* __restrict__ lev0,
                             const float* __restrict__ film,
                             float* __restrict__ out)
{
    size_t n4 = ((size_t)blockIdx.x * 256 + threadIdx.x) * 4;
    int c = (int)(n4 & (CH - 1));
    int b = (int)(n4 >> 21);  // L*C = 2^21
    float4 h = ldb4_(lev0 + n4);
    const float* fs = film + b * 512;
    float4 o;
    o.x = h.x * (1.0f + fs[c + 0]) + fs[256 + c + 0];
    o.y = h.y * (1.0f + fs[c + 1]) + fs[256 + c + 1];
    o.z = h.z * (1.0f + fs[c + 2]) + fs[256 + c + 2];
    o.w = h.w * (1.0f + fs[c + 3]) + fs[256 + c + 3];
    *(float4*)(out + n4) = o;
}

extern "C" void kernel_launch(void* const* d_in, const int* in_sizes, int n_in,
                              void* d_out, int out_size, void* d_ws, size_t ws_size,
                              hipStream_t stream) {
    const float* x       = (const float*)d_in[0];
    const float* stem_w  = (const float*)d_in[1];
    const float* stem_b  = (const float*)d_in[2];
    const float* qkv_w   = (const float*)d_in[3];
    const float* width_w = (const float*)d_in[4];
    const float* width_b = (const float*)d_in[5];
    const float* out_w   = (const float*)d_in[6];
    const float* query   = (const float*)d_in[7];
    const float* film_w  = (const float*)d_in[8];
    const float* film_b  = (const float*)d_in[9];
    float* out = (float*)d_out;
    float* ws  = (float*)d_ws;

    // ---- workspace layout (fp32 region then bf16 region) ----
    float* partials = ws;                       // 131,072
    float* denomP   = partials + 131072;        // 128
    float* ctx      = denomP + 128;             // 2,048 (unused)
    float* film     = ctx + 2048;               // 1,024
    unsigned short* x16g  = (unsigned short*)(film + 1024);  // 256 guard + 4,194,304
    unsigned short* h16_0 = x16g + 4194560;     // 4,194,304 (unused now)
    unsigned short* h16_1 = h16_0 + 4194304;    // 2,097,152
    unsigned short* h16_2 = h16_1 + 2097152;    // 1,048,576
    unsigned short* h16_3 = h16_2 + 1048576;    //   524,288
    unsigned short* qkv16 = h16_3 + 524288;     // 12,582,912 (reserved, unused)
    unsigned short* ov16  = qkv16 + 12582912;   // 4,194,304 (reserved, unused)
    unsigned short* l16_0 = ov16 + 4194304;     // 4,194,304
    unsigned short* l16_1 = l16_0 + 4194304;    // 2,097,152
    unsigned short* l16_2 = l16_1 + 2097152;    // 1,048,576
    unsigned short* l16_3 = l16_2 + 1048576;    //   524,288
    unsigned short* qw16  = l16_3 + 524288;     //   196,608
    unsigned short* ow16  = qw16 + 196608;      //    65,536 (reserved, unused)
    unsigned short* sw16  = ow16 + 65536;       //   131,072
    unsigned short* h16[4]  = {h16_0, h16_1, h16_2, h16_3};
    unsigned short* l16[4]  = {l16_0, l16_1, l16_2, l16_3};
    (void)qkv16; (void)ov16; (void)ow16; (void)ctx;

    // ---- fused prep (guard + x16 + q/k weights + stem) + Vp weight fold ----
    prep_kernel<<<NPREP_BLOCKS + 256, 256, 0, stream>>>(
        x, qkv_w, out_w, stem_w, x16g, qw16, sw16);

    // ---- hierarchy levels: ONE fused kernel per level (64-row blocks,
    //      16 waves); level 0 also computes the stem conv in-block ----
    for (int i = 0; i < NLEV; ++i) {
        const int l = L_SEQ >> i;
        const int M = B_SZ * l;
        if (i == 0)
            level_fused_kernel<1><<<M / 64, 1024, 0, stream>>>(
                h16[0], x16g, sw16, stem_b, qw16, width_w, width_b,
                l16[0], h16_1, l);
        else
            level_fused_kernel<0><<<M / 64, 1024, 0, stream>>>(
                h16[i], x16g, sw16, stem_b, qw16, width_w, width_b,
                l16[i], (i < NLEV - 1) ? h16[i + 1] : nullptr, l);
    }

    // ---- fused global-attention tail + FiLM (ctx reduction folded in) ----
    tail_ctx_kernel<<<dim3(64, B_SZ), 1024, 0, stream>>>(
        l16_0, l16_1, l16_2, l16_3, query, partials, denomP);
    film_kernel<<<128, 256, 0, stream>>>(partials, denomP, film_w, film_b, film);
    final_kernel<<<(B_SZ * L_SEQ * CH) / 1024, 256, 0, stream>>>(l16_0, film, out);
}